// Round 6
// baseline (1906.433 us; speedup 1.0000x reference)
//
#include <hip/hip_runtime.h>
#include <hip/hip_bf16.h>

#define S_SPK 2
#define BATCH 16
#define TMAX 300
#define CLASSES 3000
#define NUM_STATES 400
#define NUM_ARCS 1200
#define DEN_STATES 3000
#define DEN_ARCS 60000

#define BLK 768               // threads per forward block (12 waves)
#define NWAVE 12
#define KCH 12                // den chunks per PAIR (12*16 + 64 = 256 blocks = 1/CU)
#define CHST 250              // 3000 / 12
#define NPAIR 16              // seq pairs: (q, q+16) share seqlen[q]
#define NSEQ 32               // S_SPK * BATCH
#define NUM_CAP_G 2400        // per graph: 1200 + 3*400
#define NGRAPH 32             // (p,b) graphs

// ---------------- workspace layout (bytes) ----------------
#define WS_DEN_ARCS   0              // 72000*8   = 576000
#define WS_NUM_ARCS   576000         // 32*2400*8 = 614400 -> 1190400
#define WS_DEN_CNT    1190400        // 3000*4    -> 1202400
#define WS_DEN_R      1202400        // 3001*4    -> 1214416 (pad)
#define WS_DEN_CUR    1214416        // 3000*4    -> 1226416
#define WS_NUM_CNT    1226416        // 32*400*4  -> 1277616
#define WS_NUM_R      1277616        // 32*401*4  -> 1328944
#define WS_NUM_CUR    1328944        // 32*400*4  -> 1380144
#define WS_GALPHA     1380144        // 32*2*3000*4 = 768000 -> 2148144 (tagged)
#define WS_DEN_Z      2156592        // 32 floats -> 2156720
#define WS_NUM_Z      2156720        // 64 floats -> 2156976
#define WS_PI         2157232        // 3000*4 -> 2169232 (state -> position)
#define WS_INV        2169232        // 3000*4 -> 2181232 (position -> state)
#define WS_ZERO_INTS  (2156592 / 4)  // zero everything below den_z (incl galpha: tag=0)

// ---------------------------------------------------------------------------
__global__ void zero_ws(int* __restrict__ p, int n) {
    int i = blockIdx.x * blockDim.x + threadIdx.x;
    for (; i < n; i += gridDim.x * blockDim.x) p[i] = 0;
}

// fused histograms (den + num)
__global__ void hist_all(const int* __restrict__ dden, int* __restrict__ dcnt,
                         const int* __restrict__ dnum, int* __restrict__ ncnt) {
    int i = blockIdx.x * blockDim.x + threadIdx.x;
    if (i < DEN_ARCS) atomicAdd(&dcnt[dden[i]], 1);
    if (i < NGRAPH * NUM_ARCS) {
        int g = i / NUM_ARCS;
        atomicAdd(&ncnt[g * NUM_STATES + dnum[i]], 1);
    }
}

// ---------------------------------------------------------------------------
// Fused den preprocessing, one 1024-thread block (see R5 notes):
// counting-sort states by arc count desc, deal round-robin across KCH chunks,
// then per-POSITION x4-padded prefix -> den CSR row offsets R.
// ---------------------------------------------------------------------------
__global__ void prep_den(const int* __restrict__ cnt, int* __restrict__ pi,
                         int* __restrict__ inv, int* __restrict__ R) {
    __shared__ int bins[64], bcur[64], sc[1024];
    const int tid = threadIdx.x;

    if (tid < 64) bins[tid] = 0;
    __syncthreads();

    int c0 = 0, c1 = 0, c2 = 0;
    if (tid < 1000) {
        c0 = cnt[3 * tid]; c1 = cnt[3 * tid + 1]; c2 = cnt[3 * tid + 2];
        atomicAdd(&bins[min(c0, 63)], 1);
        atomicAdd(&bins[min(c1, 63)], 1);
        atomicAdd(&bins[min(c2, 63)], 1);
    }
    __syncthreads();

    if (tid < 64) {
        int sum = 0;
        for (int b = 63; b > tid; --b) sum += bins[b];
        bcur[tid] = sum;
    }
    __syncthreads();

    if (tid < 1000) {
        int cc[3] = { c0, c1, c2 };
        #pragma unroll
        for (int j = 0; j < 3; ++j) {
            int c = min(cc[j], 63);
            int rank = atomicAdd(&bcur[c], 1);            // rank 0 = heaviest
            int pos = (rank % KCH) * CHST + rank / KCH;   // deal across chunks
            pi[3 * tid + j] = pos;
            inv[pos] = 3 * tid + j;
        }
    }
    __syncthreads();   // inv[] globally written; visible in-block after barrier

    int d0 = 0, d1 = 0, d2 = 0, p0 = 0, p1 = 0, p2 = 0, pg = 0;
    if (tid < 1000) {
        d0 = cnt[inv[3 * tid]]; d1 = cnt[inv[3 * tid + 1]]; d2 = cnt[inv[3 * tid + 2]];
        p0 = (d0 + 3) & ~3; p1 = (d1 + 3) & ~3; p2 = (d2 + 3) & ~3;
        pg = p0 + p1 + p2;
    }
    sc[tid] = pg; __syncthreads();
    for (int o = 1; o < 1024; o <<= 1) {
        int v = (tid >= o) ? sc[tid - o] : 0;
        __syncthreads(); sc[tid] += v; __syncthreads();
    }
    int ex = sc[tid] - pg;
    if (tid < 1000) {
        R[3 * tid] = ex; R[3 * tid + 1] = ex + p0; R[3 * tid + 2] = ex + p0 + p1;
    }
    if (tid == 1000) R[3000] = ex;  // total
}

// 32 blocks x 512: per-graph padded per-state prefix (num)
__global__ void scan_num(const int* __restrict__ cnt, int* __restrict__ R) {
    __shared__ int sc[512];
    int g = blockIdx.x, tid = threadIdx.x;
    int c = 0, pg = 0;
    if (tid < NUM_STATES) { c = cnt[g * NUM_STATES + tid]; pg = (c + 3) & ~3; }
    sc[tid] = pg; __syncthreads();
    for (int o = 1; o < 512; o <<= 1) {
        int v = (tid >= o) ? sc[tid - o] : 0;
        __syncthreads(); sc[tid] += v; __syncthreads();
    }
    int ex = sc[tid] - pg;
    if (tid <= NUM_STATES) R[g * (NUM_STATES + 1) + tid] = ex;
}

// fused scatter (den + num)
__global__ void scat_all(
    const int* __restrict__ dsrc, const int* __restrict__ ddst,
    const int* __restrict__ dlab, const float* __restrict__ dw,
    const int* __restrict__ dR, int* __restrict__ dcur,
    const int* __restrict__ pi, int2* __restrict__ dout,
    const int* __restrict__ nsrc, const int* __restrict__ ndst,
    const int* __restrict__ nlab, const float* __restrict__ nw,
    const int* __restrict__ nR, int* __restrict__ ncur, int2* __restrict__ nout)
{
    int i = blockIdx.x * blockDim.x + threadIdx.x;
    if (i < DEN_ARCS) {
        int dpos = pi[ddst[i]];
        int spos = pi[dsrc[i]];
        int pos = dR[dpos] + atomicAdd(&dcur[dpos], 1);
        dout[pos] = make_int2(spos | (dlab[i] << 16), __float_as_int(__expf(dw[i])));
    }
    if (i < NGRAPH * NUM_ARCS) {
        int g = i / NUM_ARCS;
        int d = ndst[i];
        int pos = nR[g * (NUM_STATES + 1) + d] + atomicAdd(&ncur[g * NUM_STATES + d], 1);
        nout[g * NUM_CAP_G + pos] =
            make_int2(nsrc[i] | (nlab[i] << 16), __float_as_int(__expf(nw[i])));
    }
}

// ---------------------------------------------------------------------------
// num forward: single 768-thread block, prob domain, 1 state/thread
// ---------------------------------------------------------------------------
__device__ __forceinline__ void num_fwd(
    const int* __restrict__ R, const int2* __restrict__ arcs,
    const float* __restrict__ start, const float* __restrict__ fin,
    const float* __restrict__ est, int L, float* __restrict__ out,
    float* A0, float* A1, float* p, float* red)
{
    const int tid = threadIdx.x, lane = tid & 63, wid = tid >> 6;

    if (tid < NUM_STATES) A0[tid] = __expf(start[tid]);

    int rs = 0, re = 0;
    if (tid < NUM_STATES) { rs = R[tid]; re = R[tid + 1]; }

    float l0 = est[tid], l1 = est[tid + 768], l2 = est[tid + 1536];
    float l3 = (tid < 696) ? est[tid + 2304] : 0.f;

    float c = 1.f, OFF = 0.f, pend = 0.f;
    const int4* arcs4 = (const int4*)arcs;

    for (int t = 0; t < L; ++t) {
        OFF += pend;
        p[tid] = __expf(l0) * c;        p[tid + 768] = __expf(l1) * c;
        p[tid + 1536] = __expf(l2) * c;
        if (tid < 696) p[tid + 2304] = __expf(l3) * c;
        {
            const float* nr = est + (size_t)((t + 1 < L) ? (t + 1) : t) * CLASSES;
            l0 = nr[tid]; l1 = nr[tid + 768]; l2 = nr[tid + 1536];
            if (tid < 696) l3 = nr[tid + 2304];
        }
        __syncthreads();   // p ready (also protects red[] from prev iter reads)

        const float* Ac = (t & 1) ? A1 : A0;
        float*       An = (t & 1) ? A0 : A1;
        float a0 = 0.f;
        for (int r = rs; r < re; r += 4) {
            int4 q0 = arcs4[(r >> 1)];
            int4 q1 = arcs4[(r >> 1) + 1];
            a0 += Ac[q0.x & 0xffff] * p[((unsigned)q0.x) >> 16] * __int_as_float(q0.y);
            a0 += Ac[q0.z & 0xffff] * p[((unsigned)q0.z) >> 16] * __int_as_float(q0.w);
            a0 += Ac[q1.x & 0xffff] * p[((unsigned)q1.x) >> 16] * __int_as_float(q1.y);
            a0 += Ac[q1.z & 0xffff] * p[((unsigned)q1.z) >> 16] * __int_as_float(q1.w);
        }
        float mymax = 0.f;
        if (tid < NUM_STATES) { An[tid] = a0; mymax = a0; }
        #pragma unroll
        for (int o = 32; o > 0; o >>= 1) mymax = fmaxf(mymax, __shfl_down(mymax, o, 64));
        if (lane == 0) red[wid] = mymax;
        __syncthreads();
        float M = red[0];
        #pragma unroll
        for (int k = 1; k < NWAVE; ++k) M = fmaxf(M, red[k]);
        M = fmaxf(M, 1e-37f);
        c = 1.0f / M;
        pend = __logf(M);
    }

    const float* Af = (L & 1) ? A1 : A0;
    float fs = 0.f;
    if (tid < NUM_STATES) fs = Af[tid] * __expf(fin[tid]);
    __syncthreads();   // red[] settled
    #pragma unroll
    for (int o = 32; o > 0; o >>= 1) fs += __shfl_down(fs, o, 64);
    if (lane == 0) red[wid] = fs;
    __syncthreads();
    if (tid == 0) {
        float s = 0.f;
        #pragma unroll
        for (int k = 0; k < NWAVE; ++k) s += red[k];
        out[0] = OFF + __logf(s);
    }
}

// ---------------------------------------------------------------------------
// Fused forward: blocks [0,192) = den chunk*16+pair; [192,256) = num.
// Den: each block processes TWO sequences (q and q+16 — same seqlen) of the
// SAME shared den graph, chunked KCH=12 ways. Per superstep both seqs advance
// one t: the exchange chain (store -> LLC visibility -> observe) is paid once
// for two seq-steps, and each arc descriptor load + address calc drives both
// accumulators. Data-embedded tags ((t%3)+1 in 2 mantissa LSBs) as before;
// one barrier per superstep; double-buffered S1/S2 per seq.
// ---------------------------------------------------------------------------
__global__ __launch_bounds__(BLK) void forward_kernel(
    const float* __restrict__ est, const int* __restrict__ seqlen,
    const int2* __restrict__ den_arcs, const int* __restrict__ den_R,
    const float* __restrict__ den_start, const float* __restrict__ den_final,
    const int* __restrict__ den_inv,
    const int2* __restrict__ num_arcs, const int* __restrict__ num_R,
    const float* __restrict__ num_start, const float* __restrict__ num_final,
    float* __restrict__ galpha,
    float* __restrict__ den_z, float* __restrict__ num_z)
{
    __shared__ float S1A[2][DEN_STATES];
    __shared__ float S1B[2][DEN_STATES];
    __shared__ float S2A[2][CLASSES];
    __shared__ float S2B[2][CLASSES];
    __shared__ float redA[2][16], redB[2][16];

    const int blk = blockIdx.x;
    const int tid = threadIdx.x, lane = tid & 63, wid = tid >> 6;

    if (blk < KCH * NPAIR) {
        const int q = blk & 15;          // pair id; chunks of a pair share XCD residue
        const int chunk = blk >> 4;
        const int seqA = q, seqB = q + 16;   // same seqlen[q]
        const int L = seqlen[q];
        const float* estA = est + (size_t)seqA * TMAX * CLASSES;
        const float* estB = est + (size_t)seqB * TMAX * CLASSES;
        const int base = chunk * CHST;
        unsigned* gaU = (unsigned*)galpha;

        int rs = 0, re = 0;
        if (tid < CHST) { rs = den_R[base + tid]; re = den_R[base + tid + 1]; }
        const int4* arcs4 = (const int4*)den_arcs;
        const int4* ap = arcs4 + (rs >> 1);          // per-thread arc stream base
        const int n4 = (re - rs) >> 2;               // iterations (4 slots each)

        float lA0 = estA[tid], lA1 = estA[tid + 768], lA2 = estA[tid + 1536];
        float lA3 = (tid < 696) ? estA[tid + 2304] : 0.f;
        float lB0 = estB[tid], lB1 = estB[tid + 768], lB2 = estB[tid + 1536];
        float lB3 = (tid < 696) ? estB[tid + 2304] : 0.f;

        float OFFA = 0.f, OFFB = 0.f;

        for (int t = 0; t < L; ++t) {
            const int cur = t & 1;
            float* S1Ac = S1A[cur]; float* S1Bc = S1B[cur];
            float* S2Ac = S2A[cur]; float* S2Bc = S2B[cur];

            // stage p_raw = exp(llh) for both seqs; prefetch next rows
            S2Ac[tid] = __expf(lA0); S2Ac[tid + 768] = __expf(lA1);
            S2Ac[tid + 1536] = __expf(lA2);
            if (tid < 696) S2Ac[tid + 2304] = __expf(lA3);
            S2Bc[tid] = __expf(lB0); S2Bc[tid + 768] = __expf(lB1);
            S2Bc[tid + 1536] = __expf(lB2);
            if (tid < 696) S2Bc[tid + 2304] = __expf(lB3);
            {
                const size_t row = (size_t)((t + 1 < L) ? (t + 1) : t) * CLASSES;
                const float* nrA = estA + row; const float* nrB = estB + row;
                lA0 = nrA[tid]; lA1 = nrA[tid + 768]; lA2 = nrA[tid + 1536];
                if (tid < 696) lA3 = nrA[tid + 2304];
                lB0 = nrB[tid]; lB1 = nrB[tid + 768]; lB2 = nrB[tid + 1536];
                if (tid < 696) lB3 = nrB[tid + 2304];
            }

            // first two arc-iterations' descriptor loads fly during poll/barrier
            int4 d0 = ap[0], d1 = ap[1], e0 = ap[2], e1 = ap[3];

            if (t == 0) {
                float v0 = __expf(den_start[den_inv[tid]]);
                float v1 = __expf(den_start[den_inv[tid + 768]]);
                float v2 = __expf(den_start[den_inv[tid + 1536]]);
                S1Ac[tid] = v0;        S1Bc[tid] = v0;
                S1Ac[tid + 768] = v1;  S1Bc[tid + 768] = v1;
                S1Ac[tid + 1536] = v2; S1Bc[tid + 1536] = v2;
                if (tid < 696) {
                    float v3 = __expf(den_start[den_inv[tid + 2304]]);
                    S1Ac[tid + 2304] = v3; S1Bc[tid + 2304] = v3;
                }
            } else {
                // combined data-tag poll: 8 words (4 per seq), issued together
                const unsigned tg = (unsigned)((t - 1) % 3) + 1u;
                const unsigned* gpA = gaU + ((size_t)seqA * 2 + ((t - 1) & 1)) * DEN_STATES;
                const unsigned* gpB = gaU + ((size_t)seqB * 2 + ((t - 1) & 1)) * DEN_STATES;
                unsigned uA0, uA1, uA2, uA3 = tg, uB0, uB1, uB2, uB3 = tg;
                for (;;) {
                    uA0 = __hip_atomic_load(gpA + tid,        __ATOMIC_RELAXED, __HIP_MEMORY_SCOPE_AGENT);
                    uA1 = __hip_atomic_load(gpA + tid + 768,  __ATOMIC_RELAXED, __HIP_MEMORY_SCOPE_AGENT);
                    uA2 = __hip_atomic_load(gpA + tid + 1536, __ATOMIC_RELAXED, __HIP_MEMORY_SCOPE_AGENT);
                    uB0 = __hip_atomic_load(gpB + tid,        __ATOMIC_RELAXED, __HIP_MEMORY_SCOPE_AGENT);
                    uB1 = __hip_atomic_load(gpB + tid + 768,  __ATOMIC_RELAXED, __HIP_MEMORY_SCOPE_AGENT);
                    uB2 = __hip_atomic_load(gpB + tid + 1536, __ATOMIC_RELAXED, __HIP_MEMORY_SCOPE_AGENT);
                    if (tid < 696) {
                        uA3 = __hip_atomic_load(gpA + tid + 2304, __ATOMIC_RELAXED, __HIP_MEMORY_SCOPE_AGENT);
                        uB3 = __hip_atomic_load(gpB + tid + 2304, __ATOMIC_RELAXED, __HIP_MEMORY_SCOPE_AGENT);
                    }
                    bool okA = ((uA0 & 3u) == tg) && ((uA1 & 3u) == tg) &&
                               ((uA2 & 3u) == tg) && ((uA3 & 3u) == tg);
                    bool okB = ((uB0 & 3u) == tg) && ((uB1 & 3u) == tg) &&
                               ((uB2 & 3u) == tg) && ((uB3 & 3u) == tg);
                    if (okA && okB) break;
                    __builtin_amdgcn_s_sleep(1);
                }
                float xA0 = __uint_as_float(uA0 & ~3u), xA1 = __uint_as_float(uA1 & ~3u);
                float xA2 = __uint_as_float(uA2 & ~3u);
                float xA3 = (tid < 696) ? __uint_as_float(uA3 & ~3u) : 0.f;
                float xB0 = __uint_as_float(uB0 & ~3u), xB1 = __uint_as_float(uB1 & ~3u);
                float xB2 = __uint_as_float(uB2 & ~3u);
                float xB3 = (tid < 696) ? __uint_as_float(uB3 & ~3u) : 0.f;
                S1Ac[tid] = xA0; S1Ac[tid + 768] = xA1; S1Ac[tid + 1536] = xA2;
                S1Bc[tid] = xB0; S1Bc[tid + 768] = xB1; S1Bc[tid + 1536] = xB2;
                if (tid < 696) { S1Ac[tid + 2304] = xA3; S1Bc[tid + 2304] = xB3; }
                float mA = fmaxf(fmaxf(xA0, xA1), fmaxf(xA2, xA3));
                float mB = fmaxf(fmaxf(xB0, xB1), fmaxf(xB2, xB3));
                #pragma unroll
                for (int o = 32; o > 0; o >>= 1) {
                    mA = fmaxf(mA, __shfl_down(mA, o, 64));
                    mB = fmaxf(mB, __shfl_down(mB, o, 64));
                }
                if (lane == 0) { redA[cur][wid] = mA; redB[cur][wid] = mB; }
            }

            __syncthreads();   // THE one barrier per superstep

            float cMA = 1.0f, cMB = 1.0f;
            if (t) {
                const float4* rA = (const float4*)redA[cur];
                const float4* rB = (const float4*)redB[cur];
                float4 a4 = rA[0], b4 = rA[1], c4 = rA[2];
                float MA = fmaxf(fmaxf(fmaxf(a4.x, a4.y), fmaxf(a4.z, a4.w)),
                          fmaxf(fmaxf(fmaxf(b4.x, b4.y), fmaxf(b4.z, b4.w)),
                                fmaxf(fmaxf(c4.x, c4.y), fmaxf(c4.z, c4.w))));
                a4 = rB[0]; b4 = rB[1]; c4 = rB[2];
                float MB = fmaxf(fmaxf(fmaxf(a4.x, a4.y), fmaxf(a4.z, a4.w)),
                          fmaxf(fmaxf(fmaxf(b4.x, b4.y), fmaxf(b4.z, b4.w)),
                                fmaxf(fmaxf(c4.x, c4.y), fmaxf(c4.z, c4.w))));
                MA = fmaxf(MA, 1e-37f); MB = fmaxf(MB, 1e-37f);
                cMA = 1.0f / MA; cMB = 1.0f / MB;
                OFFA += __logf(MA); OFFB += __logf(MB);
            }

            // fused depth-2 software-pipelined arc loop: one descriptor stream
            // drives both sequences' accumulators
            float accA = 0.f, accB = 0.f;
            for (int i = 0; i < n4; ++i) {
                int4 p0 = ap[2 * i + 4], p1 = ap[2 * i + 5];   // 2 iters ahead
                {
                    int s = d0.x & 0xffff; unsigned c = ((unsigned)d0.x) >> 16;
                    float w = __int_as_float(d0.y);
                    accA += S1Ac[s] * S2Ac[c] * w; accB += S1Bc[s] * S2Bc[c] * w;
                }
                {
                    int s = d0.z & 0xffff; unsigned c = ((unsigned)d0.z) >> 16;
                    float w = __int_as_float(d0.w);
                    accA += S1Ac[s] * S2Ac[c] * w; accB += S1Bc[s] * S2Bc[c] * w;
                }
                {
                    int s = d1.x & 0xffff; unsigned c = ((unsigned)d1.x) >> 16;
                    float w = __int_as_float(d1.y);
                    accA += S1Ac[s] * S2Ac[c] * w; accB += S1Bc[s] * S2Bc[c] * w;
                }
                {
                    int s = d1.z & 0xffff; unsigned c = ((unsigned)d1.z) >> 16;
                    float w = __int_as_float(d1.w);
                    accA += S1Ac[s] * S2Ac[c] * w; accB += S1Bc[s] * S2Bc[c] * w;
                }
                d0 = e0; d1 = e1; e0 = p0; e1 = p1;
            }

            if (tid < CHST) {
                const unsigned tag = (unsigned)(t % 3) + 1u;
                unsigned uvA = (__float_as_uint(accA * cMA) & ~3u) | tag;
                unsigned uvB = (__float_as_uint(accB * cMB) & ~3u) | tag;
                __hip_atomic_store(gaU + ((size_t)seqA * 2 + cur) * DEN_STATES + base + tid,
                                   uvA, __ATOMIC_RELAXED, __HIP_MEMORY_SCOPE_AGENT);
                __hip_atomic_store(gaU + ((size_t)seqB * 2 + cur) * DEN_STATES + base + tid,
                                   uvB, __ATOMIC_RELAXED, __HIP_MEMORY_SCOPE_AGENT);
            }
            asm volatile("" ::: "memory");   // pin stores before next poll
        }

        // epilogue: chunk 0 computes logZ for both seqs (data-tag poll)
        if (chunk == 0) {
            __syncthreads();   // all waves past loop; red free for reuse
            const unsigned tg = (unsigned)((L - 1) % 3) + 1u;
            const unsigned* gpA = gaU + ((size_t)seqA * 2 + ((L - 1) & 1)) * DEN_STATES;
            const unsigned* gpB = gaU + ((size_t)seqB * 2 + ((L - 1) & 1)) * DEN_STATES;
            unsigned uA0, uA1, uA2, uA3 = tg, uB0, uB1, uB2, uB3 = tg;
            for (;;) {
                uA0 = __hip_atomic_load(gpA + tid,        __ATOMIC_RELAXED, __HIP_MEMORY_SCOPE_AGENT);
                uA1 = __hip_atomic_load(gpA + tid + 768,  __ATOMIC_RELAXED, __HIP_MEMORY_SCOPE_AGENT);
                uA2 = __hip_atomic_load(gpA + tid + 1536, __ATOMIC_RELAXED, __HIP_MEMORY_SCOPE_AGENT);
                uB0 = __hip_atomic_load(gpB + tid,        __ATOMIC_RELAXED, __HIP_MEMORY_SCOPE_AGENT);
                uB1 = __hip_atomic_load(gpB + tid + 768,  __ATOMIC_RELAXED, __HIP_MEMORY_SCOPE_AGENT);
                uB2 = __hip_atomic_load(gpB + tid + 1536, __ATOMIC_RELAXED, __HIP_MEMORY_SCOPE_AGENT);
                if (tid < 696) {
                    uA3 = __hip_atomic_load(gpA + tid + 2304, __ATOMIC_RELAXED, __HIP_MEMORY_SCOPE_AGENT);
                    uB3 = __hip_atomic_load(gpB + tid + 2304, __ATOMIC_RELAXED, __HIP_MEMORY_SCOPE_AGENT);
                }
                bool okA = ((uA0 & 3u) == tg) && ((uA1 & 3u) == tg) &&
                           ((uA2 & 3u) == tg) && ((uA3 & 3u) == tg);
                bool okB = ((uB0 & 3u) == tg) && ((uB1 & 3u) == tg) &&
                           ((uB2 & 3u) == tg) && ((uB3 & 3u) == tg);
                if (okA && okB) break;
                __builtin_amdgcn_s_sleep(1);
            }
            float f0 = __expf(den_final[den_inv[tid]]);
            float f1 = __expf(den_final[den_inv[tid + 768]]);
            float f2 = __expf(den_final[den_inv[tid + 1536]]);
            float fsA = __uint_as_float(uA0 & ~3u) * f0
                      + __uint_as_float(uA1 & ~3u) * f1
                      + __uint_as_float(uA2 & ~3u) * f2;
            float fsB = __uint_as_float(uB0 & ~3u) * f0
                      + __uint_as_float(uB1 & ~3u) * f1
                      + __uint_as_float(uB2 & ~3u) * f2;
            if (tid < 696) {
                float f3 = __expf(den_final[den_inv[tid + 2304]]);
                fsA += __uint_as_float(uA3 & ~3u) * f3;
                fsB += __uint_as_float(uB3 & ~3u) * f3;
            }
            #pragma unroll
            for (int o = 32; o > 0; o >>= 1) {
                fsA += __shfl_down(fsA, o, 64);
                fsB += __shfl_down(fsB, o, 64);
            }
            if (lane == 0) { redA[0][wid] = fsA; redB[0][wid] = fsB; }
            __syncthreads();
            if (tid == 0) {
                float sA = 0.f, sB = 0.f;
                #pragma unroll
                for (int k = 0; k < NWAVE; ++k) { sA += redA[0][k]; sB += redB[0][k]; }
                den_z[seqA] = OFFA + __logf(sA);
                den_z[seqB] = OFFB + __logf(sB);
            }
        }
    } else {
        const int q = blk - KCH * NPAIR;
        const int b = q & 15;
        const int sp = q >> 4;
        const int s = sp >> 1, pp = sp & 1;
        const int L = seqlen[b];
        const int g = pp * BATCH + b;
        num_fwd(num_R + (size_t)g * (NUM_STATES + 1),
                num_arcs + (size_t)g * NUM_CAP_G,
                num_start + (size_t)g * NUM_STATES,
                num_final + (size_t)g * NUM_STATES,
                est + (size_t)(s * BATCH + b) * TMAX * CLASSES, L, &num_z[q],
                &S1A[0][0], &S1A[0][1536], &S2A[0][0], &redA[0][0]);
    }
}

// ---------------------------------------------------------------------------
__global__ void loss_kernel(const float* __restrict__ den_z,
                            const float* __restrict__ num_z,
                            float* __restrict__ out)
{
    int tid = threadIdx.x;
    float l = 0.f;
    if (tid < BATCH) {
        int b = tid;
        float z00 = num_z[(0 * 2 + 0) * BATCH + b];
        float z01 = num_z[(0 * 2 + 1) * BATCH + b];
        float z10 = num_z[(1 * 2 + 0) * BATCH + b];
        float z11 = num_z[(1 * 2 + 1) * BATCH + b];
        float perm0 = z00 + z11;
        float perm1 = z01 + z10;
        float n0, n1;
        if (perm0 >= perm1) { n0 = z00; n1 = z11; }
        else                { n0 = z01; n1 = z10; }
        l = -(n0 - den_z[0 * BATCH + b]) - (n1 - den_z[1 * BATCH + b]);
    }
    #pragma unroll
    for (int o = 32; o > 0; o >>= 1) l += __shfl_down(l, o, 64);
    if (tid == 0) out[0] = l;
}

// ---------------------------------------------------------------------------
extern "C" void kernel_launch(void* const* d_in, const int* in_sizes, int n_in,
                              void* d_out, int out_size, void* d_ws, size_t ws_size,
                              hipStream_t stream) {
    const float* est        = (const float*)d_in[0];
    const int*   seqlen     = (const int*)d_in[1];
    const int*   num_src    = (const int*)d_in[2];
    const int*   num_dst    = (const int*)d_in[3];
    const int*   num_label  = (const int*)d_in[4];
    const float* num_weight = (const float*)d_in[5];
    const float* num_start  = (const float*)d_in[6];
    const float* num_final  = (const float*)d_in[7];
    const int*   den_src    = (const int*)d_in[8];
    const int*   den_dst    = (const int*)d_in[9];
    const int*   den_label  = (const int*)d_in[10];
    const float* den_weight = (const float*)d_in[11];
    const float* den_start  = (const float*)d_in[12];
    const float* den_final  = (const float*)d_in[13];

    char* ws = (char*)d_ws;
    int2*     den_arcs = (int2*)(ws + WS_DEN_ARCS);
    int2*     num_arcs = (int2*)(ws + WS_NUM_ARCS);
    int*      den_cnt  = (int*)(ws + WS_DEN_CNT);
    int*      den_R    = (int*)(ws + WS_DEN_R);
    int*      den_cur  = (int*)(ws + WS_DEN_CUR);
    int*      num_cnt  = (int*)(ws + WS_NUM_CNT);
    int*      num_R    = (int*)(ws + WS_NUM_R);
    int*      num_cur  = (int*)(ws + WS_NUM_CUR);
    float*    galpha   = (float*)(ws + WS_GALPHA);
    float*    den_z    = (float*)(ws + WS_DEN_Z);
    float*    num_z    = (float*)(ws + WS_NUM_Z);
    int*      pi       = (int*)(ws + WS_PI);
    int*      inv      = (int*)(ws + WS_INV);

    zero_ws<<<512, 256, 0, stream>>>((int*)ws, WS_ZERO_INTS);
    hist_all<<<(DEN_ARCS + 255) / 256, 256, 0, stream>>>(den_dst, den_cnt,
                                                         num_dst, num_cnt);
    prep_den<<<1, 1024, 0, stream>>>(den_cnt, pi, inv, den_R);
    scan_num<<<NGRAPH, 512, 0, stream>>>(num_cnt, num_R);
    scat_all<<<(DEN_ARCS + 255) / 256, 256, 0, stream>>>(
        den_src, den_dst, den_label, den_weight, den_R, den_cur, pi, den_arcs,
        num_src, num_dst, num_label, num_weight, num_R, num_cur, num_arcs);

    forward_kernel<<<KCH * NPAIR + S_SPK * S_SPK * BATCH, BLK, 0, stream>>>(
        est, seqlen, den_arcs, den_R, den_start, den_final, inv,
        num_arcs, num_R, num_start, num_final,
        galpha, den_z, num_z);

    loss_kernel<<<1, 64, 0, stream>>>(den_z, num_z, (float*)d_out);
}

// Round 7
// 1558.512 us; speedup vs baseline: 1.2232x; 1.2232x over previous
//
#include <hip/hip_runtime.h>
#include <hip/hip_bf16.h>

#define S_SPK 2
#define BATCH 16
#define TMAX 300
#define CLASSES 3000
#define NUM_STATES 400
#define NUM_ARCS 1200
#define DEN_STATES 3000
#define DEN_ARCS 60000

#define BLK 768               // threads per forward block (12 waves)
#define NWAVE 12
#define KCH 6                 // den chunks per sequence (6*32 + 64 = 256 blocks = 1/CU)
#define CHST 500              // 3000 / 6
#define NSEQ 32               // S_SPK * BATCH
#define NUM_CAP_G 2400        // per graph: 1200 + 3*400
#define NGRAPH 32             // (p,b) graphs
#define REDPAD 9216           // widen red[] to pad LDS to ~122KB -> 1 block/CU

// ---------------- workspace layout (bytes) ----------------
#define WS_DEN_ARCS   0              // 72000*8   = 576000
#define WS_NUM_ARCS   576000         // 32*2400*8 = 614400 -> 1190400
#define WS_DEN_CNT    1190400        // 3000*4    -> 1202400
#define WS_DEN_R      1202400        // 3001*4    -> 1214416 (pad)
#define WS_DEN_CUR    1214416        // 3000*4    -> 1226416
#define WS_NUM_CNT    1226416        // 32*400*4  -> 1277616
#define WS_NUM_R      1277616        // 32*401*4  -> 1328944
#define WS_NUM_CUR    1328944        // 32*400*4  -> 1380144
#define WS_GALPHA     1380144        // 32*2*3000*4 = 768000 -> 2148144 (tagged)
#define WS_DEN_Z      2156592        // 32 floats -> 2156720
#define WS_NUM_Z      2156720        // 64 floats -> 2156976
#define WS_PI         2157232        // 3000*4 -> 2169232 (state -> position)
#define WS_INV        2169232        // 3000*4 -> 2181232 (position -> state)
#define WS_ZERO_INTS  (2156592 / 4)  // zero everything below den_z (incl galpha: tag=0)

// ---------------------------------------------------------------------------
__global__ void zero_ws(int* __restrict__ p, int n) {
    int i = blockIdx.x * blockDim.x + threadIdx.x;
    for (; i < n; i += gridDim.x * blockDim.x) p[i] = 0;
}

// fused histograms (den + num)
__global__ void hist_all(const int* __restrict__ dden, int* __restrict__ dcnt,
                         const int* __restrict__ dnum, int* __restrict__ ncnt) {
    int i = blockIdx.x * blockDim.x + threadIdx.x;
    if (i < DEN_ARCS) atomicAdd(&dcnt[dden[i]], 1);
    if (i < NGRAPH * NUM_ARCS) {
        int g = i / NUM_ARCS;
        atomicAdd(&ncnt[g * NUM_STATES + dnum[i]], 1);
    }
}

// ---------------------------------------------------------------------------
// Fused den preprocessing, one 1024-thread block:
// counting-sort states by arc count desc, deal round-robin across KCH chunks,
// then per-POSITION x4-padded prefix -> den CSR row offsets R.
// ---------------------------------------------------------------------------
__global__ void prep_den(const int* __restrict__ cnt, int* __restrict__ pi,
                         int* __restrict__ inv, int* __restrict__ R) {
    __shared__ int bins[64], bcur[64], sc[1024];
    const int tid = threadIdx.x;

    if (tid < 64) bins[tid] = 0;
    __syncthreads();

    int c0 = 0, c1 = 0, c2 = 0;
    if (tid < 1000) {
        c0 = cnt[3 * tid]; c1 = cnt[3 * tid + 1]; c2 = cnt[3 * tid + 2];
        atomicAdd(&bins[min(c0, 63)], 1);
        atomicAdd(&bins[min(c1, 63)], 1);
        atomicAdd(&bins[min(c2, 63)], 1);
    }
    __syncthreads();

    if (tid < 64) {
        int sum = 0;
        for (int b = 63; b > tid; --b) sum += bins[b];
        bcur[tid] = sum;
    }
    __syncthreads();

    if (tid < 1000) {
        int cc[3] = { c0, c1, c2 };
        #pragma unroll
        for (int j = 0; j < 3; ++j) {
            int c = min(cc[j], 63);
            int rank = atomicAdd(&bcur[c], 1);            // rank 0 = heaviest
            int pos = (rank % KCH) * CHST + rank / KCH;   // deal across chunks
            pi[3 * tid + j] = pos;
            inv[pos] = 3 * tid + j;
        }
    }
    __syncthreads();   // inv[] globally written; visible in-block after barrier

    int d0 = 0, d1 = 0, d2 = 0, p0 = 0, p1 = 0, p2 = 0, pg = 0;
    if (tid < 1000) {
        d0 = cnt[inv[3 * tid]]; d1 = cnt[inv[3 * tid + 1]]; d2 = cnt[inv[3 * tid + 2]];
        p0 = (d0 + 3) & ~3; p1 = (d1 + 3) & ~3; p2 = (d2 + 3) & ~3;
        pg = p0 + p1 + p2;
    }
    sc[tid] = pg; __syncthreads();
    for (int o = 1; o < 1024; o <<= 1) {
        int v = (tid >= o) ? sc[tid - o] : 0;
        __syncthreads(); sc[tid] += v; __syncthreads();
    }
    int ex = sc[tid] - pg;
    if (tid < 1000) {
        R[3 * tid] = ex; R[3 * tid + 1] = ex + p0; R[3 * tid + 2] = ex + p0 + p1;
    }
    if (tid == 1000) R[3000] = ex;  // total
}

// 32 blocks x 512: per-graph padded per-state prefix (num)
__global__ void scan_num(const int* __restrict__ cnt, int* __restrict__ R) {
    __shared__ int sc[512];
    int g = blockIdx.x, tid = threadIdx.x;
    int c = 0, pg = 0;
    if (tid < NUM_STATES) { c = cnt[g * NUM_STATES + tid]; pg = (c + 3) & ~3; }
    sc[tid] = pg; __syncthreads();
    for (int o = 1; o < 512; o <<= 1) {
        int v = (tid >= o) ? sc[tid - o] : 0;
        __syncthreads(); sc[tid] += v; __syncthreads();
    }
    int ex = sc[tid] - pg;
    if (tid <= NUM_STATES) R[g * (NUM_STATES + 1) + tid] = ex;
}

// fused scatter (den + num)
__global__ void scat_all(
    const int* __restrict__ dsrc, const int* __restrict__ ddst,
    const int* __restrict__ dlab, const float* __restrict__ dw,
    const int* __restrict__ dR, int* __restrict__ dcur,
    const int* __restrict__ pi, int2* __restrict__ dout,
    const int* __restrict__ nsrc, const int* __restrict__ ndst,
    const int* __restrict__ nlab, const float* __restrict__ nw,
    const int* __restrict__ nR, int* __restrict__ ncur, int2* __restrict__ nout)
{
    int i = blockIdx.x * blockDim.x + threadIdx.x;
    if (i < DEN_ARCS) {
        int dpos = pi[ddst[i]];
        int spos = pi[dsrc[i]];
        int pos = dR[dpos] + atomicAdd(&dcur[dpos], 1);
        dout[pos] = make_int2(spos | (dlab[i] << 16), __float_as_int(__expf(dw[i])));
    }
    if (i < NGRAPH * NUM_ARCS) {
        int g = i / NUM_ARCS;
        int d = ndst[i];
        int pos = nR[g * (NUM_STATES + 1) + d] + atomicAdd(&ncur[g * NUM_STATES + d], 1);
        nout[g * NUM_CAP_G + pos] =
            make_int2(nsrc[i] | (nlab[i] << 16), __float_as_int(__expf(nw[i])));
    }
}

// ---------------------------------------------------------------------------
// num forward: single 768-thread block, prob domain, 1 state/thread
// ---------------------------------------------------------------------------
__device__ __forceinline__ void num_fwd(
    const int* __restrict__ R, const int2* __restrict__ arcs,
    const float* __restrict__ start, const float* __restrict__ fin,
    const float* __restrict__ est, int L, float* __restrict__ out,
    float* A0, float* A1, float* p, float* red)
{
    const int tid = threadIdx.x, lane = tid & 63, wid = tid >> 6;

    if (tid < NUM_STATES) A0[tid] = __expf(start[tid]);

    int rs = 0, re = 0;
    if (tid < NUM_STATES) { rs = R[tid]; re = R[tid + 1]; }

    float l0 = est[tid], l1 = est[tid + 768], l2 = est[tid + 1536];
    float l3 = (tid < 696) ? est[tid + 2304] : 0.f;

    float c = 1.f, OFF = 0.f, pend = 0.f;
    const int4* arcs4 = (const int4*)arcs;

    for (int t = 0; t < L; ++t) {
        OFF += pend;
        p[tid] = __expf(l0) * c;        p[tid + 768] = __expf(l1) * c;
        p[tid + 1536] = __expf(l2) * c;
        if (tid < 696) p[tid + 2304] = __expf(l3) * c;
        {
            const float* nr = est + (size_t)((t + 1 < L) ? (t + 1) : t) * CLASSES;
            l0 = nr[tid]; l1 = nr[tid + 768]; l2 = nr[tid + 1536];
            if (tid < 696) l3 = nr[tid + 2304];
        }
        __syncthreads();   // p ready (also protects red[] from prev iter reads)

        const float* Ac = (t & 1) ? A1 : A0;
        float*       An = (t & 1) ? A0 : A1;
        float a0 = 0.f;
        for (int r = rs; r < re; r += 4) {
            int4 q0 = arcs4[(r >> 1)];
            int4 q1 = arcs4[(r >> 1) + 1];
            a0 += Ac[q0.x & 0xffff] * p[((unsigned)q0.x) >> 16] * __int_as_float(q0.y);
            a0 += Ac[q0.z & 0xffff] * p[((unsigned)q0.z) >> 16] * __int_as_float(q0.w);
            a0 += Ac[q1.x & 0xffff] * p[((unsigned)q1.x) >> 16] * __int_as_float(q1.y);
            a0 += Ac[q1.z & 0xffff] * p[((unsigned)q1.z) >> 16] * __int_as_float(q1.w);
        }
        float mymax = 0.f;
        if (tid < NUM_STATES) { An[tid] = a0; mymax = a0; }
        #pragma unroll
        for (int o = 32; o > 0; o >>= 1) mymax = fmaxf(mymax, __shfl_down(mymax, o, 64));
        if (lane == 0) red[wid] = mymax;
        __syncthreads();
        float M = red[0];
        #pragma unroll
        for (int k = 1; k < NWAVE; ++k) M = fmaxf(M, red[k]);
        M = fmaxf(M, 1e-37f);
        c = 1.0f / M;
        pend = __logf(M);
    }

    const float* Af = (L & 1) ? A1 : A0;
    float fs = 0.f;
    if (tid < NUM_STATES) fs = Af[tid] * __expf(fin[tid]);
    __syncthreads();   // red[] settled
    #pragma unroll
    for (int o = 32; o > 0; o >>= 1) fs += __shfl_down(fs, o, 64);
    if (lane == 0) red[wid] = fs;
    __syncthreads();
    if (tid == 0) {
        float s = 0.f;
        #pragma unroll
        for (int k = 0; k < NWAVE; ++k) s += red[k];
        out[0] = OFF + __logf(s);
    }
}

// ---------------------------------------------------------------------------
// Fused forward: blocks [0,192) = den chunk*32+seq; [192,256) = num.
// Den: KCH=6 chunks exchange alpha per step via LLC with DATA-EMBEDDED TAGS
// (2 mantissa LSBs = (t%3)+1; never 0 = zeroed buffer). One barrier/step,
// double-buffered S1/S2/red; depth-2 software-pipelined arc loop with the
// first 2 iterations' loads issued before the poll.
// R7: LDS padded (red widened) to ~122KB so exactly ONE block fits per CU —
// prevents two den chunks co-residing on a CU and halving each other's LDS
// bandwidth; in the lockstep exchange one slow chunk gates all seqs.
// 256 blocks = 256 CUs, all co-resident (R6 proved schedulability at 96KB).
// ---------------------------------------------------------------------------
__global__ __launch_bounds__(BLK) void forward_kernel(
    const float* __restrict__ est, const int* __restrict__ seqlen,
    const int2* __restrict__ den_arcs, const int* __restrict__ den_R,
    const float* __restrict__ den_start, const float* __restrict__ den_final,
    const int* __restrict__ den_inv,
    const int2* __restrict__ num_arcs, const int* __restrict__ num_R,
    const float* __restrict__ num_start, const float* __restrict__ num_final,
    float* __restrict__ galpha,
    float* __restrict__ den_z, float* __restrict__ num_z)
{
    __shared__ float S1[2][DEN_STATES];   // den: alpha (double-buffered) | num: A0/A1
    __shared__ float S2[2][CLASSES];      // den: p (double-buffered)     | num: p
    __shared__ float red[2][REDPAD];      // only [..][0..15] used; pad -> 1 blk/CU

    const int blk = blockIdx.x;
    const int tid = threadIdx.x, lane = tid & 63, wid = tid >> 6;

    if (blk < KCH * NSEQ) {
        const int seq = blk & 31;        // chunks of a seq share XCD residue
        const int chunk = blk >> 5;
        const int b = seq & 15;
        const int L = seqlen[b];
        const float* est_base = est + (size_t)seq * TMAX * CLASSES;
        const int base = chunk * CHST;
        unsigned* gaU = (unsigned*)galpha;

        int rs = 0, re = 0;
        if (tid < CHST) { rs = den_R[base + tid]; re = den_R[base + tid + 1]; }
        const int4* arcs4 = (const int4*)den_arcs;
        const int4* ap = arcs4 + (rs >> 1);          // per-thread arc stream base
        const int n4 = (re - rs) >> 2;               // iterations (4 slots each)

        float l0 = est_base[tid], l1 = est_base[tid + 768], l2 = est_base[tid + 1536];
        float l3 = (tid < 696) ? est_base[tid + 2304] : 0.f;

        float OFF = 0.f;

        for (int t = 0; t < L; ++t) {
            const int cur = t & 1;
            float* S1c = S1[cur];
            float* S2c = S2[cur];

            // stage p_raw = exp(llh); prefetch next row (overlaps poll)
            S2c[tid] = __expf(l0); S2c[tid + 768] = __expf(l1); S2c[tid + 1536] = __expf(l2);
            if (tid < 696) S2c[tid + 2304] = __expf(l3);
            {
                const float* nr = est_base + (size_t)((t + 1 < L) ? (t + 1) : t) * CLASSES;
                l0 = nr[tid]; l1 = nr[tid + 768]; l2 = nr[tid + 1536];
                if (tid < 696) l3 = nr[tid + 2304];
            }

            // issue the first two arc-iterations' loads NOW: their L2 latency
            // hides under the poll + barrier
            int4 a0 = ap[0], a1 = ap[1], b0 = ap[2], b1 = ap[3];

            if (t == 0) {
                S1c[tid]        = __expf(den_start[den_inv[tid]]);
                S1c[tid + 768]  = __expf(den_start[den_inv[tid + 768]]);
                S1c[tid + 1536] = __expf(den_start[den_inv[tid + 1536]]);
                if (tid < 696) S1c[tid + 2304] = __expf(den_start[den_inv[tid + 2304]]);
            } else {
                // per-thread data-tag poll on its own 4 gather words
                const unsigned tg = (unsigned)((t - 1) % 3) + 1u;
                const unsigned* gp = gaU + ((size_t)seq * 2 + ((t - 1) & 1)) * DEN_STATES;
                unsigned u0, u1, u2, u3 = tg;   // synthetic match for tid>=696
                for (;;) {
                    u0 = __hip_atomic_load(gp + tid,        __ATOMIC_RELAXED, __HIP_MEMORY_SCOPE_AGENT);
                    u1 = __hip_atomic_load(gp + tid + 768,  __ATOMIC_RELAXED, __HIP_MEMORY_SCOPE_AGENT);
                    u2 = __hip_atomic_load(gp + tid + 1536, __ATOMIC_RELAXED, __HIP_MEMORY_SCOPE_AGENT);
                    if (tid < 696)
                        u3 = __hip_atomic_load(gp + tid + 2304, __ATOMIC_RELAXED, __HIP_MEMORY_SCOPE_AGENT);
                    if ((((u0 & 3u) == tg) && ((u1 & 3u) == tg)) &&
                        (((u2 & 3u) == tg) && ((u3 & 3u) == tg))) break;
                    __builtin_amdgcn_s_sleep(1);
                }
                float x0 = __uint_as_float(u0 & ~3u);
                float x1 = __uint_as_float(u1 & ~3u);
                float x2 = __uint_as_float(u2 & ~3u);
                float x3 = (tid < 696) ? __uint_as_float(u3 & ~3u) : 0.f;
                S1c[tid] = x0; S1c[tid + 768] = x1; S1c[tid + 1536] = x2;
                if (tid < 696) S1c[tid + 2304] = x3;
                // wave-level partial max (block combine deferred past barrier)
                float mymax = fmaxf(fmaxf(x0, x1), fmaxf(x2, x3));
                #pragma unroll
                for (int o = 32; o > 0; o >>= 1)
                    mymax = fmaxf(mymax, __shfl_down(mymax, o, 64));
                if (lane == 0) red[cur][wid] = mymax;
            }

            __syncthreads();   // THE one barrier: S1c,S2c,red[cur] ready

            // combine block max FIRST (3x b128 broadcast reads), so the store
            // can issue immediately after the arc loop's last FMA
            float cM = 1.0f;
            if (t) {
                const float4* r4 = (const float4*)red[cur];
                float4 ra = r4[0], rb = r4[1], rc = r4[2];
                float M = fmaxf(fmaxf(fmaxf(ra.x, ra.y), fmaxf(ra.z, ra.w)),
                         fmaxf(fmaxf(fmaxf(rb.x, rb.y), fmaxf(rb.z, rb.w)),
                               fmaxf(fmaxf(rc.x, rc.y), fmaxf(rc.z, rc.w))));
                M = fmaxf(M, 1e-37f);
                cM = 1.0f / M;
                OFF += __logf(M);
            }

            // depth-2 software-pipelined arc loop
            float acc = 0.f;
            for (int i = 0; i < n4; ++i) {
                int4 p0 = ap[2 * i + 4], p1 = ap[2 * i + 5];   // 2 iters ahead
                acc += S1c[a0.x & 0xffff] * S2c[((unsigned)a0.x) >> 16] * __int_as_float(a0.y);
                acc += S1c[a0.z & 0xffff] * S2c[((unsigned)a0.z) >> 16] * __int_as_float(a0.w);
                acc += S1c[a1.x & 0xffff] * S2c[((unsigned)a1.x) >> 16] * __int_as_float(a1.y);
                acc += S1c[a1.z & 0xffff] * S2c[((unsigned)a1.z) >> 16] * __int_as_float(a1.w);
                a0 = b0; a1 = b1; b0 = p0; b1 = p1;
            }

            if (tid < CHST) {
                unsigned uv = (__float_as_uint(acc * cM) & ~3u) | ((unsigned)(t % 3) + 1u);
                __hip_atomic_store(gaU + ((size_t)seq * 2 + cur) * DEN_STATES + base + tid,
                                   uv, __ATOMIC_RELAXED, __HIP_MEMORY_SCOPE_AGENT);
            }
            asm volatile("" ::: "memory");   // pin the store before next poll
        }

        // epilogue: chunk 0 computes logZ from final buffer (data-tag poll)
        if (chunk == 0) {
            __syncthreads();   // all waves past loop; red free for reuse
            const unsigned tg = (unsigned)((L - 1) % 3) + 1u;
            const unsigned* gp = gaU + ((size_t)seq * 2 + ((L - 1) & 1)) * DEN_STATES;
            unsigned u0, u1, u2, u3 = tg;
            for (;;) {
                u0 = __hip_atomic_load(gp + tid,        __ATOMIC_RELAXED, __HIP_MEMORY_SCOPE_AGENT);
                u1 = __hip_atomic_load(gp + tid + 768,  __ATOMIC_RELAXED, __HIP_MEMORY_SCOPE_AGENT);
                u2 = __hip_atomic_load(gp + tid + 1536, __ATOMIC_RELAXED, __HIP_MEMORY_SCOPE_AGENT);
                if (tid < 696)
                    u3 = __hip_atomic_load(gp + tid + 2304, __ATOMIC_RELAXED, __HIP_MEMORY_SCOPE_AGENT);
                if ((((u0 & 3u) == tg) && ((u1 & 3u) == tg)) &&
                    (((u2 & 3u) == tg) && ((u3 & 3u) == tg))) break;
                __builtin_amdgcn_s_sleep(1);
            }
            float fs = __uint_as_float(u0 & ~3u) * __expf(den_final[den_inv[tid]])
                     + __uint_as_float(u1 & ~3u) * __expf(den_final[den_inv[tid + 768]])
                     + __uint_as_float(u2 & ~3u) * __expf(den_final[den_inv[tid + 1536]]);
            if (tid < 696)
                fs += __uint_as_float(u3 & ~3u) * __expf(den_final[den_inv[tid + 2304]]);
            #pragma unroll
            for (int o = 32; o > 0; o >>= 1) fs += __shfl_down(fs, o, 64);
            if (lane == 0) red[0][wid] = fs;
            __syncthreads();
            if (tid == 0) {
                float s = 0.f;
                #pragma unroll
                for (int k = 0; k < NWAVE; ++k) s += red[0][k];
                den_z[seq] = OFF + __logf(s);
            }
        }
    } else {
        const int q = blk - KCH * NSEQ;
        const int b = q & 15;
        const int sp = q >> 4;
        const int s = sp >> 1, pp = sp & 1;
        const int L = seqlen[b];
        const int g = pp * BATCH + b;
        num_fwd(num_R + (size_t)g * (NUM_STATES + 1),
                num_arcs + (size_t)g * NUM_CAP_G,
                num_start + (size_t)g * NUM_STATES,
                num_final + (size_t)g * NUM_STATES,
                est + (size_t)(s * BATCH + b) * TMAX * CLASSES, L, &num_z[q],
                &S1[0][0], &S1[0][1536], &S2[0][0], &red[0][0]);
    }
}

// ---------------------------------------------------------------------------
__global__ void loss_kernel(const float* __restrict__ den_z,
                            const float* __restrict__ num_z,
                            float* __restrict__ out)
{
    int tid = threadIdx.x;
    float l = 0.f;
    if (tid < BATCH) {
        int b = tid;
        float z00 = num_z[(0 * 2 + 0) * BATCH + b];
        float z01 = num_z[(0 * 2 + 1) * BATCH + b];
        float z10 = num_z[(1 * 2 + 0) * BATCH + b];
        float z11 = num_z[(1 * 2 + 1) * BATCH + b];
        float perm0 = z00 + z11;
        float perm1 = z01 + z10;
        float n0, n1;
        if (perm0 >= perm1) { n0 = z00; n1 = z11; }
        else                { n0 = z01; n1 = z10; }
        l = -(n0 - den_z[0 * BATCH + b]) - (n1 - den_z[1 * BATCH + b]);
    }
    #pragma unroll
    for (int o = 32; o > 0; o >>= 1) l += __shfl_down(l, o, 64);
    if (tid == 0) out[0] = l;
}

// ---------------------------------------------------------------------------
extern "C" void kernel_launch(void* const* d_in, const int* in_sizes, int n_in,
                              void* d_out, int out_size, void* d_ws, size_t ws_size,
                              hipStream_t stream) {
    const float* est        = (const float*)d_in[0];
    const int*   seqlen     = (const int*)d_in[1];
    const int*   num_src    = (const int*)d_in[2];
    const int*   num_dst    = (const int*)d_in[3];
    const int*   num_label  = (const int*)d_in[4];
    const float* num_weight = (const float*)d_in[5];
    const float* num_start  = (const float*)d_in[6];
    const float* num_final  = (const float*)d_in[7];
    const int*   den_src    = (const int*)d_in[8];
    const int*   den_dst    = (const int*)d_in[9];
    const int*   den_label  = (const int*)d_in[10];
    const float* den_weight = (const float*)d_in[11];
    const float* den_start  = (const float*)d_in[12];
    const float* den_final  = (const float*)d_in[13];

    char* ws = (char*)d_ws;
    int2*     den_arcs = (int2*)(ws + WS_DEN_ARCS);
    int2*     num_arcs = (int2*)(ws + WS_NUM_ARCS);
    int*      den_cnt  = (int*)(ws + WS_DEN_CNT);
    int*      den_R    = (int*)(ws + WS_DEN_R);
    int*      den_cur  = (int*)(ws + WS_DEN_CUR);
    int*      num_cnt  = (int*)(ws + WS_NUM_CNT);
    int*      num_R    = (int*)(ws + WS_NUM_R);
    int*      num_cur  = (int*)(ws + WS_NUM_CUR);
    float*    galpha   = (float*)(ws + WS_GALPHA);
    float*    den_z    = (float*)(ws + WS_DEN_Z);
    float*    num_z    = (float*)(ws + WS_NUM_Z);
    int*      pi       = (int*)(ws + WS_PI);
    int*      inv      = (int*)(ws + WS_INV);

    zero_ws<<<512, 256, 0, stream>>>((int*)ws, WS_ZERO_INTS);
    hist_all<<<(DEN_ARCS + 255) / 256, 256, 0, stream>>>(den_dst, den_cnt,
                                                         num_dst, num_cnt);
    prep_den<<<1, 1024, 0, stream>>>(den_cnt, pi, inv, den_R);
    scan_num<<<NGRAPH, 512, 0, stream>>>(num_cnt, num_R);
    scat_all<<<(DEN_ARCS + 255) / 256, 256, 0, stream>>>(
        den_src, den_dst, den_label, den_weight, den_R, den_cur, pi, den_arcs,
        num_src, num_dst, num_label, num_weight, num_R, num_cur, num_arcs);

    forward_kernel<<<KCH * NSEQ + S_SPK * S_SPK * BATCH, BLK, 0, stream>>>(
        est, seqlen, den_arcs, den_R, den_start, den_final, inv,
        num_arcs, num_R, num_start, num_final,
        galpha, den_z, num_z);

    loss_kernel<<<1, 64, 0, stream>>>(den_z, num_z, (float*)d_out);
}

// Round 8
// 1525.606 us; speedup vs baseline: 1.2496x; 1.0216x over previous
//
#include <hip/hip_runtime.h>
#include <hip/hip_bf16.h>

#define S_SPK 2
#define BATCH 16
#define TMAX 300
#define CLASSES 3000
#define NUM_STATES 400
#define NUM_ARCS 1200
#define DEN_STATES 3000
#define DEN_ARCS 60000

#define BLK 768               // threads per forward block (12 waves)
#define NWAVE 12
#define KCH 6                 // den chunks per sequence (6*32 + 64 = 256 blocks = 1/CU)
#define CHST 500              // 3000 / 6
#define NSEQ 32               // S_SPK * BATCH
#define NUM_CAP_G 2400        // per graph: 1200 + 3*400
#define NGRAPH 32             // (p,b) graphs
#define REDPAD 9216           // widen red[] to pad LDS to ~122KB -> 1 block/CU

// ---------------- workspace layout (bytes) ----------------
#define WS_DEN_ARCS   0              // 72000*8   = 576000
#define WS_NUM_ARCS   576000         // 32*2400*8 = 614400 -> 1190400
#define WS_DEN_CNT    1190400        // 3000*4    -> 1202400
#define WS_DEN_R      1202400        // 3001*4    -> 1214416 (pad)
#define WS_DEN_CUR    1214416        // 3000*4    -> 1226416
#define WS_NUM_CNT    1226416        // 32*400*4  -> 1277616
#define WS_NUM_R      1277616        // 32*401*4  -> 1328944
#define WS_NUM_CUR    1328944        // 32*400*4  -> 1380144
#define WS_GALPHA     1380144        // 32*2*3000*4 = 768000 -> 2148144 (tagged)
#define WS_DEN_Z      2156592        // 32 floats -> 2156720
#define WS_NUM_Z      2156720        // 64 floats -> 2156976
#define WS_PI         2157232        // 3000*4 -> 2169232 (state -> position)
#define WS_INV        2169232        // 3000*4 -> 2181232 (position -> state)
#define WS_ZERO_INTS  (2156592 / 4)  // zero everything below den_z (incl galpha: tag=0)

// ---------------------------------------------------------------------------
__global__ void zero_ws(int* __restrict__ p, int n) {
    int i = blockIdx.x * blockDim.x + threadIdx.x;
    for (; i < n; i += gridDim.x * blockDim.x) p[i] = 0;
}

// fused histograms (den + num)
__global__ void hist_all(const int* __restrict__ dden, int* __restrict__ dcnt,
                         const int* __restrict__ dnum, int* __restrict__ ncnt) {
    int i = blockIdx.x * blockDim.x + threadIdx.x;
    if (i < DEN_ARCS) atomicAdd(&dcnt[dden[i]], 1);
    if (i < NGRAPH * NUM_ARCS) {
        int g = i / NUM_ARCS;
        atomicAdd(&ncnt[g * NUM_STATES + dnum[i]], 1);
    }
}

// ---------------------------------------------------------------------------
// Fused den preprocessing, one 1024-thread block:
// counting-sort states by arc count desc, deal round-robin across KCH chunks,
// then per-POSITION x4-padded prefix -> den CSR row offsets R.
// ---------------------------------------------------------------------------
__global__ void prep_den(const int* __restrict__ cnt, int* __restrict__ pi,
                         int* __restrict__ inv, int* __restrict__ R) {
    __shared__ int bins[64], bcur[64], sc[1024];
    const int tid = threadIdx.x;

    if (tid < 64) bins[tid] = 0;
    __syncthreads();

    int c0 = 0, c1 = 0, c2 = 0;
    if (tid < 1000) {
        c0 = cnt[3 * tid]; c1 = cnt[3 * tid + 1]; c2 = cnt[3 * tid + 2];
        atomicAdd(&bins[min(c0, 63)], 1);
        atomicAdd(&bins[min(c1, 63)], 1);
        atomicAdd(&bins[min(c2, 63)], 1);
    }
    __syncthreads();

    if (tid < 64) {
        int sum = 0;
        for (int b = 63; b > tid; --b) sum += bins[b];
        bcur[tid] = sum;
    }
    __syncthreads();

    if (tid < 1000) {
        int cc[3] = { c0, c1, c2 };
        #pragma unroll
        for (int j = 0; j < 3; ++j) {
            int c = min(cc[j], 63);
            int rank = atomicAdd(&bcur[c], 1);            // rank 0 = heaviest
            int pos = (rank % KCH) * CHST + rank / KCH;   // deal across chunks
            pi[3 * tid + j] = pos;
            inv[pos] = 3 * tid + j;
        }
    }
    __syncthreads();   // inv[] globally written; visible in-block after barrier

    int d0 = 0, d1 = 0, d2 = 0, p0 = 0, p1 = 0, p2 = 0, pg = 0;
    if (tid < 1000) {
        d0 = cnt[inv[3 * tid]]; d1 = cnt[inv[3 * tid + 1]]; d2 = cnt[inv[3 * tid + 2]];
        p0 = (d0 + 3) & ~3; p1 = (d1 + 3) & ~3; p2 = (d2 + 3) & ~3;
        pg = p0 + p1 + p2;
    }
    sc[tid] = pg; __syncthreads();
    for (int o = 1; o < 1024; o <<= 1) {
        int v = (tid >= o) ? sc[tid - o] : 0;
        __syncthreads(); sc[tid] += v; __syncthreads();
    }
    int ex = sc[tid] - pg;
    if (tid < 1000) {
        R[3 * tid] = ex; R[3 * tid + 1] = ex + p0; R[3 * tid + 2] = ex + p0 + p1;
    }
    if (tid == 1000) R[3000] = ex;  // total
}

// 32 blocks x 512: per-graph padded per-state prefix (num)
__global__ void scan_num(const int* __restrict__ cnt, int* __restrict__ R) {
    __shared__ int sc[512];
    int g = blockIdx.x, tid = threadIdx.x;
    int c = 0, pg = 0;
    if (tid < NUM_STATES) { c = cnt[g * NUM_STATES + tid]; pg = (c + 3) & ~3; }
    sc[tid] = pg; __syncthreads();
    for (int o = 1; o < 512; o <<= 1) {
        int v = (tid >= o) ? sc[tid - o] : 0;
        __syncthreads(); sc[tid] += v; __syncthreads();
    }
    int ex = sc[tid] - pg;
    if (tid <= NUM_STATES) R[g * (NUM_STATES + 1) + tid] = ex;
}

// fused scatter (den + num)
__global__ void scat_all(
    const int* __restrict__ dsrc, const int* __restrict__ ddst,
    const int* __restrict__ dlab, const float* __restrict__ dw,
    const int* __restrict__ dR, int* __restrict__ dcur,
    const int* __restrict__ pi, int2* __restrict__ dout,
    const int* __restrict__ nsrc, const int* __restrict__ ndst,
    const int* __restrict__ nlab, const float* __restrict__ nw,
    const int* __restrict__ nR, int* __restrict__ ncur, int2* __restrict__ nout)
{
    int i = blockIdx.x * blockDim.x + threadIdx.x;
    if (i < DEN_ARCS) {
        int dpos = pi[ddst[i]];
        int spos = pi[dsrc[i]];
        int pos = dR[dpos] + atomicAdd(&dcur[dpos], 1);
        dout[pos] = make_int2(spos | (dlab[i] << 16), __float_as_int(__expf(dw[i])));
    }
    if (i < NGRAPH * NUM_ARCS) {
        int g = i / NUM_ARCS;
        int d = ndst[i];
        int pos = nR[g * (NUM_STATES + 1) + d] + atomicAdd(&ncur[g * NUM_STATES + d], 1);
        nout[g * NUM_CAP_G + pos] =
            make_int2(nsrc[i] | (nlab[i] << 16), __float_as_int(__expf(nw[i])));
    }
}

// ---------------------------------------------------------------------------
// num forward: single 768-thread block, prob domain, 1 state/thread
// ---------------------------------------------------------------------------
__device__ __forceinline__ void num_fwd(
    const int* __restrict__ R, const int2* __restrict__ arcs,
    const float* __restrict__ start, const float* __restrict__ fin,
    const float* __restrict__ est, int L, float* __restrict__ out,
    float* A0, float* A1, float* p, float* red)
{
    const int tid = threadIdx.x, lane = tid & 63, wid = tid >> 6;

    if (tid < NUM_STATES) A0[tid] = __expf(start[tid]);

    int rs = 0, re = 0;
    if (tid < NUM_STATES) { rs = R[tid]; re = R[tid + 1]; }

    float l0 = est[tid], l1 = est[tid + 768], l2 = est[tid + 1536];
    float l3 = (tid < 696) ? est[tid + 2304] : 0.f;

    float c = 1.f, OFF = 0.f, pend = 0.f;
    const int4* arcs4 = (const int4*)arcs;

    for (int t = 0; t < L; ++t) {
        OFF += pend;
        p[tid] = __expf(l0) * c;        p[tid + 768] = __expf(l1) * c;
        p[tid + 1536] = __expf(l2) * c;
        if (tid < 696) p[tid + 2304] = __expf(l3) * c;
        {
            const float* nr = est + (size_t)((t + 1 < L) ? (t + 1) : t) * CLASSES;
            l0 = nr[tid]; l1 = nr[tid + 768]; l2 = nr[tid + 1536];
            if (tid < 696) l3 = nr[tid + 2304];
        }
        __syncthreads();   // p ready (also protects red[] from prev iter reads)

        const float* Ac = (t & 1) ? A1 : A0;
        float*       An = (t & 1) ? A0 : A1;
        float a0 = 0.f;
        for (int r = rs; r < re; r += 4) {
            int4 q0 = arcs4[(r >> 1)];
            int4 q1 = arcs4[(r >> 1) + 1];
            a0 += Ac[q0.x & 0xffff] * p[((unsigned)q0.x) >> 16] * __int_as_float(q0.y);
            a0 += Ac[q0.z & 0xffff] * p[((unsigned)q0.z) >> 16] * __int_as_float(q0.w);
            a0 += Ac[q1.x & 0xffff] * p[((unsigned)q1.x) >> 16] * __int_as_float(q1.y);
            a0 += Ac[q1.z & 0xffff] * p[((unsigned)q1.z) >> 16] * __int_as_float(q1.w);
        }
        float mymax = 0.f;
        if (tid < NUM_STATES) { An[tid] = a0; mymax = a0; }
        #pragma unroll
        for (int o = 32; o > 0; o >>= 1) mymax = fmaxf(mymax, __shfl_down(mymax, o, 64));
        if (lane == 0) red[wid] = mymax;
        __syncthreads();
        float M = red[0];
        #pragma unroll
        for (int k = 1; k < NWAVE; ++k) M = fmaxf(M, red[k]);
        M = fmaxf(M, 1e-37f);
        c = 1.0f / M;
        pend = __logf(M);
    }

    const float* Af = (L & 1) ? A1 : A0;
    float fs = 0.f;
    if (tid < NUM_STATES) fs = Af[tid] * __expf(fin[tid]);
    __syncthreads();   // red[] settled
    #pragma unroll
    for (int o = 32; o > 0; o >>= 1) fs += __shfl_down(fs, o, 64);
    if (lane == 0) red[wid] = fs;
    __syncthreads();
    if (tid == 0) {
        float s = 0.f;
        #pragma unroll
        for (int k = 0; k < NWAVE; ++k) s += red[k];
        out[0] = OFF + __logf(s);
    }
}

// ---------------------------------------------------------------------------
// Fused forward: blocks [0,192) = den chunk*32+seq; [192,256) = num.
// Den: KCH=6 chunks exchange alpha per step via LLC with DATA-EMBEDDED TAGS
// (2 mantissa LSBs = (t%3)+1; never 0 = zeroed buffer). One barrier/step,
// double-buffered S1/S2/red; depth-2 software-pipelined arc loop.
// R8: SUBSET POLLING — each thread keeps per-word done-flags and reloads ONLY
// the words whose tag hasn't matched yet (matched values are final by the tag
// protocol). Cuts steady-state agent-scope poll traffic ~3-6x (words of
// already-arrived chunks drop out of the retry stream) without touching the
// serial path: same single barrier, same tags, same success-path data flow.
// This also discriminates the mechanism pinning the 4.66us step: traffic-
// proportional speedup => LLC poll-bandwidth saturation; flat => serial
// latency floor.
// ---------------------------------------------------------------------------
__global__ __launch_bounds__(BLK) void forward_kernel(
    const float* __restrict__ est, const int* __restrict__ seqlen,
    const int2* __restrict__ den_arcs, const int* __restrict__ den_R,
    const float* __restrict__ den_start, const float* __restrict__ den_final,
    const int* __restrict__ den_inv,
    const int2* __restrict__ num_arcs, const int* __restrict__ num_R,
    const float* __restrict__ num_start, const float* __restrict__ num_final,
    float* __restrict__ galpha,
    float* __restrict__ den_z, float* __restrict__ num_z)
{
    __shared__ float S1[2][DEN_STATES];   // den: alpha (double-buffered) | num: A0/A1
    __shared__ float S2[2][CLASSES];      // den: p (double-buffered)     | num: p
    __shared__ float red[2][REDPAD];      // only [..][0..15] used; pad -> 1 blk/CU

    const int blk = blockIdx.x;
    const int tid = threadIdx.x, lane = tid & 63, wid = tid >> 6;

    if (blk < KCH * NSEQ) {
        const int seq = blk & 31;        // chunks of a seq share XCD residue
        const int chunk = blk >> 5;
        const int b = seq & 15;
        const int L = seqlen[b];
        const float* est_base = est + (size_t)seq * TMAX * CLASSES;
        const int base = chunk * CHST;
        unsigned* gaU = (unsigned*)galpha;

        int rs = 0, re = 0;
        if (tid < CHST) { rs = den_R[base + tid]; re = den_R[base + tid + 1]; }
        const int4* arcs4 = (const int4*)den_arcs;
        const int4* ap = arcs4 + (rs >> 1);          // per-thread arc stream base
        const int n4 = (re - rs) >> 2;               // iterations (4 slots each)

        float l0 = est_base[tid], l1 = est_base[tid + 768], l2 = est_base[tid + 1536];
        float l3 = (tid < 696) ? est_base[tid + 2304] : 0.f;

        float OFF = 0.f;

        for (int t = 0; t < L; ++t) {
            const int cur = t & 1;
            float* S1c = S1[cur];
            float* S2c = S2[cur];

            // stage p_raw = exp(llh); prefetch next row (overlaps poll)
            S2c[tid] = __expf(l0); S2c[tid + 768] = __expf(l1); S2c[tid + 1536] = __expf(l2);
            if (tid < 696) S2c[tid + 2304] = __expf(l3);
            {
                const float* nr = est_base + (size_t)((t + 1 < L) ? (t + 1) : t) * CLASSES;
                l0 = nr[tid]; l1 = nr[tid + 768]; l2 = nr[tid + 1536];
                if (tid < 696) l3 = nr[tid + 2304];
            }

            // issue the first two arc-iterations' loads NOW: their L2 latency
            // hides under the poll + barrier
            int4 a0 = ap[0], a1 = ap[1], b0 = ap[2], b1 = ap[3];

            if (t == 0) {
                S1c[tid]        = __expf(den_start[den_inv[tid]]);
                S1c[tid + 768]  = __expf(den_start[den_inv[tid + 768]]);
                S1c[tid + 1536] = __expf(den_start[den_inv[tid + 1536]]);
                if (tid < 696) S1c[tid + 2304] = __expf(den_start[den_inv[tid + 2304]]);
            } else {
                // subset data-tag poll: reload ONLY unmatched words
                const unsigned tg = (unsigned)((t - 1) % 3) + 1u;
                const unsigned* gp = gaU + ((size_t)seq * 2 + ((t - 1) & 1)) * DEN_STATES;
                unsigned u0 = 0, u1 = 0, u2 = 0, u3 = tg;   // synthetic match tid>=696
                bool n0 = true, n1 = true, n2 = true, n3 = (tid < 696);
                for (;;) {
                    if (n0) u0 = __hip_atomic_load(gp + tid,        __ATOMIC_RELAXED, __HIP_MEMORY_SCOPE_AGENT);
                    if (n1) u1 = __hip_atomic_load(gp + tid + 768,  __ATOMIC_RELAXED, __HIP_MEMORY_SCOPE_AGENT);
                    if (n2) u2 = __hip_atomic_load(gp + tid + 1536, __ATOMIC_RELAXED, __HIP_MEMORY_SCOPE_AGENT);
                    if (n3) u3 = __hip_atomic_load(gp + tid + 2304, __ATOMIC_RELAXED, __HIP_MEMORY_SCOPE_AGENT);
                    n0 = n0 && ((u0 & 3u) != tg);
                    n1 = n1 && ((u1 & 3u) != tg);
                    n2 = n2 && ((u2 & 3u) != tg);
                    n3 = n3 && ((u3 & 3u) != tg);
                    if (!(n0 || n1 || n2 || n3)) break;
                    __builtin_amdgcn_s_sleep(1);
                }
                float x0 = __uint_as_float(u0 & ~3u);
                float x1 = __uint_as_float(u1 & ~3u);
                float x2 = __uint_as_float(u2 & ~3u);
                float x3 = (tid < 696) ? __uint_as_float(u3 & ~3u) : 0.f;
                S1c[tid] = x0; S1c[tid + 768] = x1; S1c[tid + 1536] = x2;
                if (tid < 696) S1c[tid + 2304] = x3;
                // wave-level partial max (block combine deferred past barrier)
                float mymax = fmaxf(fmaxf(x0, x1), fmaxf(x2, x3));
                #pragma unroll
                for (int o = 32; o > 0; o >>= 1)
                    mymax = fmaxf(mymax, __shfl_down(mymax, o, 64));
                if (lane == 0) red[cur][wid] = mymax;
            }

            __syncthreads();   // THE one barrier: S1c,S2c,red[cur] ready

            // combine block max FIRST (3x b128 broadcast reads), so the store
            // can issue immediately after the arc loop's last FMA
            float cM = 1.0f;
            if (t) {
                const float4* r4 = (const float4*)red[cur];
                float4 ra = r4[0], rb = r4[1], rc = r4[2];
                float M = fmaxf(fmaxf(fmaxf(ra.x, ra.y), fmaxf(ra.z, ra.w)),
                         fmaxf(fmaxf(fmaxf(rb.x, rb.y), fmaxf(rb.z, rb.w)),
                               fmaxf(fmaxf(rc.x, rc.y), fmaxf(rc.z, rc.w))));
                M = fmaxf(M, 1e-37f);
                cM = 1.0f / M;
                OFF += __logf(M);
            }

            // depth-2 software-pipelined arc loop
            float acc = 0.f;
            for (int i = 0; i < n4; ++i) {
                int4 p0 = ap[2 * i + 4], p1 = ap[2 * i + 5];   // 2 iters ahead
                acc += S1c[a0.x & 0xffff] * S2c[((unsigned)a0.x) >> 16] * __int_as_float(a0.y);
                acc += S1c[a0.z & 0xffff] * S2c[((unsigned)a0.z) >> 16] * __int_as_float(a0.w);
                acc += S1c[a1.x & 0xffff] * S2c[((unsigned)a1.x) >> 16] * __int_as_float(a1.y);
                acc += S1c[a1.z & 0xffff] * S2c[((unsigned)a1.z) >> 16] * __int_as_float(a1.w);
                a0 = b0; a1 = b1; b0 = p0; b1 = p1;
            }

            if (tid < CHST) {
                unsigned uv = (__float_as_uint(acc * cM) & ~3u) | ((unsigned)(t % 3) + 1u);
                __hip_atomic_store(gaU + ((size_t)seq * 2 + cur) * DEN_STATES + base + tid,
                                   uv, __ATOMIC_RELAXED, __HIP_MEMORY_SCOPE_AGENT);
            }
            asm volatile("" ::: "memory");   // pin the store before next poll
        }

        // epilogue: chunk 0 computes logZ from final buffer (subset tag poll)
        if (chunk == 0) {
            __syncthreads();   // all waves past loop; red free for reuse
            const unsigned tg = (unsigned)((L - 1) % 3) + 1u;
            const unsigned* gp = gaU + ((size_t)seq * 2 + ((L - 1) & 1)) * DEN_STATES;
            unsigned u0 = 0, u1 = 0, u2 = 0, u3 = tg;
            bool n0 = true, n1 = true, n2 = true, n3 = (tid < 696);
            for (;;) {
                if (n0) u0 = __hip_atomic_load(gp + tid,        __ATOMIC_RELAXED, __HIP_MEMORY_SCOPE_AGENT);
                if (n1) u1 = __hip_atomic_load(gp + tid + 768,  __ATOMIC_RELAXED, __HIP_MEMORY_SCOPE_AGENT);
                if (n2) u2 = __hip_atomic_load(gp + tid + 1536, __ATOMIC_RELAXED, __HIP_MEMORY_SCOPE_AGENT);
                if (n3) u3 = __hip_atomic_load(gp + tid + 2304, __ATOMIC_RELAXED, __HIP_MEMORY_SCOPE_AGENT);
                n0 = n0 && ((u0 & 3u) != tg);
                n1 = n1 && ((u1 & 3u) != tg);
                n2 = n2 && ((u2 & 3u) != tg);
                n3 = n3 && ((u3 & 3u) != tg);
                if (!(n0 || n1 || n2 || n3)) break;
                __builtin_amdgcn_s_sleep(1);
            }
            float fs = __uint_as_float(u0 & ~3u) * __expf(den_final[den_inv[tid]])
                     + __uint_as_float(u1 & ~3u) * __expf(den_final[den_inv[tid + 768]])
                     + __uint_as_float(u2 & ~3u) * __expf(den_final[den_inv[tid + 1536]]);
            if (tid < 696)
                fs += __uint_as_float(u3 & ~3u) * __expf(den_final[den_inv[tid + 2304]]);
            #pragma unroll
            for (int o = 32; o > 0; o >>= 1) fs += __shfl_down(fs, o, 64);
            if (lane == 0) red[0][wid] = fs;
            __syncthreads();
            if (tid == 0) {
                float s = 0.f;
                #pragma unroll
                for (int k = 0; k < NWAVE; ++k) s += red[0][k];
                den_z[seq] = OFF + __logf(s);
            }
        }
    } else {
        const int q = blk - KCH * NSEQ;
        const int b = q & 15;
        const int sp = q >> 4;
        const int s = sp >> 1, pp = sp & 1;
        const int L = seqlen[b];
        const int g = pp * BATCH + b;
        num_fwd(num_R + (size_t)g * (NUM_STATES + 1),
                num_arcs + (size_t)g * NUM_CAP_G,
                num_start + (size_t)g * NUM_STATES,
                num_final + (size_t)g * NUM_STATES,
                est + (size_t)(s * BATCH + b) * TMAX * CLASSES, L, &num_z[q],
                &S1[0][0], &S1[0][1536], &S2[0][0], &red[0][0]);
    }
}

// ---------------------------------------------------------------------------
__global__ void loss_kernel(const float* __restrict__ den_z,
                            const float* __restrict__ num_z,
                            float* __restrict__ out)
{
    int tid = threadIdx.x;
    float l = 0.f;
    if (tid < BATCH) {
        int b = tid;
        float z00 = num_z[(0 * 2 + 0) * BATCH + b];
        float z01 = num_z[(0 * 2 + 1) * BATCH + b];
        float z10 = num_z[(1 * 2 + 0) * BATCH + b];
        float z11 = num_z[(1 * 2 + 1) * BATCH + b];
        float perm0 = z00 + z11;
        float perm1 = z01 + z10;
        float n0, n1;
        if (perm0 >= perm1) { n0 = z00; n1 = z11; }
        else                { n0 = z01; n1 = z10; }
        l = -(n0 - den_z[0 * BATCH + b]) - (n1 - den_z[1 * BATCH + b]);
    }
    #pragma unroll
    for (int o = 32; o > 0; o >>= 1) l += __shfl_down(l, o, 64);
    if (tid == 0) out[0] = l;
}

// ---------------------------------------------------------------------------
extern "C" void kernel_launch(void* const* d_in, const int* in_sizes, int n_in,
                              void* d_out, int out_size, void* d_ws, size_t ws_size,
                              hipStream_t stream) {
    const float* est        = (const float*)d_in[0];
    const int*   seqlen     = (const int*)d_in[1];
    const int*   num_src    = (const int*)d_in[2];
    const int*   num_dst    = (const int*)d_in[3];
    const int*   num_label  = (const int*)d_in[4];
    const float* num_weight = (const float*)d_in[5];
    const float* num_start  = (const float*)d_in[6];
    const float* num_final  = (const float*)d_in[7];
    const int*   den_src    = (const int*)d_in[8];
    const int*   den_dst    = (const int*)d_in[9];
    const int*   den_label  = (const int*)d_in[10];
    const float* den_weight = (const float*)d_in[11];
    const float* den_start  = (const float*)d_in[12];
    const float* den_final  = (const float*)d_in[13];

    char* ws = (char*)d_ws;
    int2*     den_arcs = (int2*)(ws + WS_DEN_ARCS);
    int2*     num_arcs = (int2*)(ws + WS_NUM_ARCS);
    int*      den_cnt  = (int*)(ws + WS_DEN_CNT);
    int*      den_R    = (int*)(ws + WS_DEN_R);
    int*      den_cur  = (int*)(ws + WS_DEN_CUR);
    int*      num_cnt  = (int*)(ws + WS_NUM_CNT);
    int*      num_R    = (int*)(ws + WS_NUM_R);
    int*      num_cur  = (int*)(ws + WS_NUM_CUR);
    float*    galpha   = (float*)(ws + WS_GALPHA);
    float*    den_z    = (float*)(ws + WS_DEN_Z);
    float*    num_z    = (float*)(ws + WS_NUM_Z);
    int*      pi       = (int*)(ws + WS_PI);
    int*      inv      = (int*)(ws + WS_INV);

    zero_ws<<<512, 256, 0, stream>>>((int*)ws, WS_ZERO_INTS);
    hist_all<<<(DEN_ARCS + 255) / 256, 256, 0, stream>>>(den_dst, den_cnt,
                                                         num_dst, num_cnt);
    prep_den<<<1, 1024, 0, stream>>>(den_cnt, pi, inv, den_R);
    scan_num<<<NGRAPH, 512, 0, stream>>>(num_cnt, num_R);
    scat_all<<<(DEN_ARCS + 255) / 256, 256, 0, stream>>>(
        den_src, den_dst, den_label, den_weight, den_R, den_cur, pi, den_arcs,
        num_src, num_dst, num_label, num_weight, num_R, num_cur, num_arcs);

    forward_kernel<<<KCH * NSEQ + S_SPK * S_SPK * BATCH, BLK, 0, stream>>>(
        est, seqlen, den_arcs, den_R, den_start, den_final, inv,
        num_arcs, num_R, num_start, num_final,
        galpha, den_z, num_z);

    loss_kernel<<<1, 64, 0, stream>>>(den_z, num_z, (float*)d_out);
}